// Round 16
// baseline (133.761 us; speedup 1.0000x reference)
//
#include <hip/hip_runtime.h>
#include <stdint.h>

// ===========================================================================
// AnchorDataGenerator (Faster R-CNN anchor target layer), MI355X / gfx950
// Round 19: serial-tail collapse. R18 proved k_one (~43us) is phase-chain
// bound, not latency bound (2x occupancy -> no change). Key output property:
// labels/wts are ~constant (IGN/0) except <=256 kept + boundary anchors.
// New structure (single dispatch, no grid-wide wake at all):
//   compute pass: adj writes + DEFAULT lab=2.0/wts=0 for all anchors EXCEPT
//     "potentially kept" (FG; BG with m<BG_TC, 18x-margin filter) -> those
//     are pushed (post-ZFLAG-gate) into 64-group fanned lists and skipped
//     (disjoint writers). Coarse hist + per-block totals as in champion.
//   barrier B arrival -> 1151 blocks EXIT. Root completer alone:
//     totals -> hist-scan select (champion verbatim, results in LDS) ->
//     process ~3K pushed candidates (parallel AG loads): below-boundary ->
//     kept values, boundary-bin -> exact LDS rank, above/mode0 -> defaults.
// Eliminated: CFLG wake broadcast, second emit pass, barrier D, fixup wait.
// Kept verbatim: analytic gmax, IoU pass, coarse-filtered 256-bin hist,
// tree arrival (64x18), ZFLAG poison-safe init (block 0 zeroes ctrl via
// AGENT stores; completer clears ZFLAG at end), vmcnt(0) before arrivals.
// ===========================================================================

#define NUM_A 9
#define HW 65536
#define N_ANCH 589824
#define NG 64
#define CAPK 128u
#define NBINS 256
#define BG_TC 65536u                     // BG coarse filter threshold on m
#define CLCAP 128u                       // per-group candidate list cap
#define STAGE_CAP 2048u

#define LAB_BG 0u
#define LAB_FG 1u
#define LAB_IGN 2u

#define NBLK 1152                        // 9 types x 128 row-pairs
#define NGRP 64                          // fan-out groups
#define GQ 18                            // blocks per group

// workspace layout (u32 words)
#define OFF_HF    0                      // 256 fg hist (full range, >>15)
#define OFF_HB    256                    // 256 bg hist ([0,2^16), >>8)
#define OFF_TOTF  512                    // 64 x stride16 per-group fg totals
#define OFF_TOTB  1536                   // 64 x stride16 bg totals
#define OFF_SUBB  2560                   // 64 x stride16 barrier-B subs
#define OFF_ROOTB 3584                   // (pad 16)
#define OFF_CCNTF 3600                   // 64 x stride16 push counters fg
#define OFF_CCNTB 4624                   // 64 x stride16 push counters bg
#define CTRL_WORDS 5648                  // zeroed by block 0 (AG stores)
#define OFF_ZFLG  CTRL_WORDS             // 5648: 64 x stride16; completer
                                         //   clears at end (lifecycle-safe)
#define OFF_LISTF (OFF_ZFLG + 64*16)     // 6672 (even -> 8B aligned)
#define OFF_LISTB (OFF_LISTF + 2*NGRP*CLCAP)  // 23056; end 39440 (~158 KB)

#define MAGIC_Z 0x7A3F19C5u

__constant__ float BA[NUM_A][4] = {
  { -84.f,  -40.f,  99.f,  55.f}, {-176.f,  -88.f, 191.f, 103.f},
  {-360.f, -184.f, 375.f, 199.f}, { -56.f,  -56.f,  71.f,  71.f},
  {-120.f, -120.f, 135.f, 135.f}, {-248.f, -248.f, 263.f, 263.f},
  { -36.f,  -80.f,  51.f,  95.f}, { -80.f, -168.f,  95.f, 183.f},
  {-168.f, -344.f, 183.f, 359.f}};

__host__ __device__ static inline void tf2x32(uint32_t k0, uint32_t k1,
                                              uint32_t x0, uint32_t x1,
                                              uint32_t* o0, uint32_t* o1) {
  const uint32_t ks2 = k0 ^ k1 ^ 0x1BD11BDAu;
#define TF_R(r) { x0 += x1; x1 = (x1 << (r)) | (x1 >> (32 - (r))); x1 ^= x0; }
  x0 += k0; x1 += k1;
  TF_R(13) TF_R(15) TF_R(26) TF_R(6)
  x0 += k1;  x1 += ks2 + 1u;
  TF_R(17) TF_R(29) TF_R(16) TF_R(24)
  x0 += ks2; x1 += k0 + 2u;
  TF_R(13) TF_R(15) TF_R(26) TF_R(6)
  x0 += k0;  x1 += k1 + 3u;
  TF_R(17) TF_R(29) TF_R(16) TF_R(24)
  x0 += k1;  x1 += ks2 + 4u;
  TF_R(13) TF_R(15) TF_R(26) TF_R(6)
  x0 += ks2; x1 += k0 + 5u;
#undef TF_R
  *o0 = x0; *o1 = x1;
}

__device__ static inline uint32_t mant_of(uint32_t k0, uint32_t k1, uint32_t n) {
  uint32_t o0, o1;
  tf2x32(k0, k1, 0u, n, &o0, &o1);
  return (o0 ^ o1) >> 9;                 // 23-bit mantissa
}

// Max of fl(iw) over valid integer shifts [lo,hi] for one axis (concave,
// unimodal; max at clamped floor/ceil of continuous argmax endpoints).
__device__ static inline float axis_best(float blo, float bhi, float glo,
                                         float ghi, int lo, int hi) {
  #pragma clang fp contract(off)
  float t1 = (ghi - bhi) * 0.0625f;
  float t2 = (glo - blo) * 0.0625f;
  float tmin = fminf(t1, t2), tmax = fmaxf(t1, t2);
  int c1 = (int)floorf(tmin), c2 = (int)ceilf(tmax);
  int cand0 = lo, cand1 = hi;
  int cand2 = min(max(c1,     lo), hi);
  int cand3 = min(max(c1 + 1, lo), hi);
  int cand4 = min(max(c2 - 1, lo), hi);
  int cand5 = min(max(c2,     lo), hi);
  float best = -3.0e38f;
  int cands[6] = {cand0, cand1, cand2, cand3, cand4, cand5};
  #pragma unroll
  for (int i = 0; i < 6; i++) {
    float s = (float)(cands[i] << 4);
    float v = fminf(bhi + s, ghi) - fmaxf(blo + s, glo) + 1.0f;
    best = fmaxf(best, v);
  }
  return best;
}

#define AG_LOAD(p)      __hip_atomic_load((p), __ATOMIC_RELAXED, __HIP_MEMORY_SCOPE_AGENT)
#define AG_STORE(p, v)  __hip_atomic_store((p), (v), __ATOMIC_RELAXED, __HIP_MEMORY_SCOPE_AGENT)

__global__ __launch_bounds__(256) void k_one(const float* __restrict__ gt,
                                             const int* __restrict__ imw_p,
                                             const int* __restrict__ imh_p,
                                             float* __restrict__ out_lab,
                                             float* __restrict__ out_adj,
                                             float* __restrict__ out_wts,
                                             uint32_t* __restrict__ ws,
                                             uint32_t kf0, uint32_t kf1,
                                             uint32_t kb0, uint32_t kb1) {
  #pragma clang fp contract(off)
  __shared__ uint64_t scB[STAGE_CAP];        // 16 KB; hist/scan/stage aliased
  uint32_t* sh = (uint32_t*)scB;             // [0..511] LDS hist, scan buf
  __shared__ float sg0[NG], sg1[NG], sg2[NG], sg3[NG], sga[NG], sgm[NG];
  __shared__ uint32_t sgmU[NG];
  __shared__ unsigned long long sMask[4];
  __shared__ int sAnyZero, sLastB;
  __shared__ uint32_t sCF, sCB;
  __shared__ uint32_t sTots[2 * NGRP];       // completer: totals
  __shared__ uint32_t sCnt2[NGRP];           // completer: list counts
  __shared__ uint32_t sSelLoc[10];           // {mode,bb,pvC,need,K} x2
  __shared__ uint32_t sStageCnt;
  __shared__ float sInv;
  int tid = threadIdx.x;
  int b = blockIdx.x;
  int a = b >> 7, hb = (b & 127) << 1;       // anchor type, rows hb, hb+1
  int grp = b & (NGRP - 1);

  // ---- block 0: zero ctrl region (AGENT stores -> at IF), fanned ZFLAG ----
  if (b == 0) {
    for (int i = tid; i < CTRL_WORDS; i += 256) AG_STORE(&ws[i], 0u);
    asm volatile("s_waitcnt vmcnt(0)" ::: "memory");
    __syncthreads();
    if (tid < NGRP) AG_STORE(&ws[OFF_ZFLG + tid * 16], MAGIC_Z);
  }

  ((uint2*)sh)[tid] = make_uint2(0, 0);      // zero 512-word LDS hist
  if (tid == 0) { sAnyZero = 0; sCF = 0u; sCB = 0u; }
  if (tid < NG) {
    const float4 g4 = ((const float4*)gt)[tid];
    sg0[tid] = g4.x; sg1[tid] = g4.y; sg2[tid] = g4.z; sg3[tid] = g4.w;
    float gw = g4.z - g4.x + 1.0f, gh = g4.w - g4.y + 1.0f;
    sga[tid] = (gw > 0.0f && gh > 0.0f) ? gw * gh : 0.0f;
    sgmU[tid] = 0u;
  }
  __syncthreads();   // S1

  // ---- local analytic gmax (LDS atomicMax on float bits; IoU >= 0) ----
  {
    int imwi = imw_p[0], imhi = imh_p[0];
    for (int p = tid; p < NG * NUM_A; p += 256) {
      int g = p / NUM_A, q = p - g * NUM_A;
      float b0 = BA[q][0], b1 = BA[q][1], b2 = BA[q][2], b3 = BA[q][3];
      int ib0 = (int)b0, ib1 = (int)b1, ib2 = (int)b2, ib3 = (int)b3;
      int wlo = max(0, (-ib0 + 15) >> 4);
      int whi = min(255, (imwi - ib2 - 1) >> 4);
      int hlo = max(0, (-ib1 + 15) >> 4);
      int hhi = min(255, (imhi - ib3 - 1) >> 4);
      if (wlo > whi || hlo > hhi) continue;
      float iwb = axis_best(b0, b2, sg0[g], sg2[g], wlo, whi);
      float ihb = axis_best(b1, b3, sg1[g], sg3[g], hlo, hhi);
      float aw = b2 - b0 + 1.0f, ah = b3 - b1 + 1.0f;
      float aarea = aw * ah;
      float inter = (iwb > 0.0f && ihb > 0.0f) ? iwb * ihb : 0.0f;
      float den = aarea + sga[g] - inter;
      float o = inter / den;
      atomicMax(&sgmU[g], __float_as_uint(o));
    }
  }

  // per-wave y-mask (waves 0,1 used)
  {
    int wv = tid >> 6, g = tid & 63;
    float sy = (float)((hb + wv) << 4);
    float ihp = fminf(BA[a][3] + sy, sg3[g]) - fmaxf(BA[a][1] + sy, sg1[g]) + 1.0f;
    unsigned long long mk = __ballot(ihp > 0.0f);
    if (g == 0) sMask[wv] = mk;
  }
  __syncthreads();   // S2
  if (tid < NG) {
    uint32_t mm = sgmU[tid];
    sgm[tid] = __uint_as_float(mm);
    if (mm == 0u) atomicOr(&sAnyZero, 1);
  }
  __syncthreads();   // S3

  float BA0 = BA[a][0], BA1 = BA[a][1], BA2 = BA[a][2], BA3 = BA[a][3];
  float imw = (float)imw_p[0], imh = (float)imh_p[0];
  int w = tid;
  float sx = (float)(w << 4);
  float A0 = BA0 + sx, A2 = BA2 + sx;
  float aw = A2 - A0 + 1.0f;
  float A1v[2], A3v[2];
  #pragma unroll
  for (int r = 0; r < 2; r++) {
    float sy = (float)((hb + r) << 4);
    A1v[r] = BA1 + sy; A3v[r] = BA3 + sy;
  }
  float ah = A3v[0] - A1v[0] + 1.0f;
  float aarea = aw * ah;                   // exact ints -> bit-exact
  bool xv = (A0 >= 0.0f) && (A2 < imw);

  unsigned long long mk0 = sMask[0], mk1 = sMask[1];
  unsigned long long uni = mk0 | mk1;
  float amaxv[2] = {0.f, 0.f};
  int bgv[2] = {0, 0};
  uint32_t afv = 0u;
  while (uni) {
    int g = __ffsll(uni) - 1;
    uni &= uni - 1;
    float iw = fminf(A2, sg2[g]) - fmaxf(A0, sg0[g]) + 1.0f;
    if (!__any(iw > 0.0f)) continue;
    if (iw > 0.0f) {
      float base = aarea + sga[g];
      float gy1 = sg1[g], gy2 = sg3[g], gm = sgm[g];
#define DO_ROW(r, mk)                                                     \
      if ((mk >> g) & 1ull) {                                             \
        float ih = fminf(A3v[r], gy2) - fmaxf(A1v[r], gy1) + 1.0f;        \
        float inter = iw * ih;                                            \
        float o = inter / (base - inter);                                 \
        if (o > amaxv[r]) { amaxv[r] = o; bgv[r] = g; }                   \
        if (o == gm) afv |= (1u << r);                                    \
      }
      DO_ROW(0, mk0) DO_ROW(1, mk1)
#undef DO_ROW
    }
  }

  bool anyZ = (sAnyZero != 0);
  uint32_t lm[2];
  uint32_t cfLoc = 0, cbLoc = 0;
  #pragma unroll
  for (int r = 0; r < 2; r++) {
    int hw = (hb + r) * 256 + w;
    bool valid = xv && (A1v[r] >= 0.0f) && (A3v[r] < imh);
    float amax = amaxv[r];
    bool anyfg = (((afv >> r) & 1u) || anyZ) && valid;
    uint32_t lab;
    if (!valid)                       lab = LAB_IGN;
    else if (anyfg || amax >= 0.7f)   lab = LAB_FG;
    else if (amax < 0.3f)             lab = LAB_BG;
    else                              lab = LAB_IGN;

    float adj0 = 0.f, adj1 = 0.f, adj2 = 0.f, adj3 = 0.f;
    if (valid) {
      int bg = bgv[r];
      float G0 = sg0[bg], G1 = sg1[bg], G2 = sg2[bg], G3 = sg3[bg];
      float ax = (A2 + A0) * 0.5f, ay = (A3v[r] + A1v[r]) * 0.5f;
      float gwm = G2 - G0 + 1.0f, ghm = G3 - G1 + 1.0f;
      float gx = (G2 + G0) * 0.5f, gy = (G3 + G1) * 0.5f;
      adj0 = (gx - ax) / aw;
      adj1 = (gy - ay) / ah;
      adj2 = logf(gwm / aw);
      adj3 = logf(ghm / ah);
    }
    int c4 = a * 4;
    out_adj[(c4 + 0) * HW + hw] = adj0;
    out_adj[(c4 + 1) * HW + hw] = adj1;
    out_adj[(c4 + 2) * HW + hw] = adj2;
    out_adj[(c4 + 3) * HW + hw] = adj3;

    uint32_t m = 0u;
    uint32_t n = (uint32_t)(hw * 9 + a);   // original anchor index (tie-break)
    if (lab != LAB_IGN) {
      uint32_t kk0 = (lab == LAB_FG) ? kf0 : kb0;
      uint32_t kk1 = (lab == LAB_FG) ? kf1 : kb1;
      m = mant_of(kk0, kk1, n);
      if (lab == LAB_FG) {
        cfLoc++;
        atomicAdd(&sh[m >> 15], 1u);                   // FG: full range >>15
      } else {
        cbLoc++;
        if (m < BG_TC) atomicAdd(&sh[NBINS + (m >> 8)], 1u);  // BG: coarse
      }
    }
    lm[r] = (lab << 24) | m;                 // stays in registers

    // DEFAULT emit for non-candidates (select-independent; candidates get
    // their outputs from the completer -> disjoint writers)
    bool cand = (lab == LAB_FG) || (lab == LAB_BG && m < BG_TC);
    if (!cand) {
      out_lab[a * HW + hw] = 2.0f;
      out_wts[(c4 + 0) * HW + hw] = 0.0f;
      out_wts[(c4 + 1) * HW + hw] = 0.0f;
      out_wts[(c4 + 2) * HW + hw] = 0.0f;
      out_wts[(c4 + 3) * HW + hw] = 0.0f;
    }
  }
  if (cfLoc) atomicAdd(&sCF, cfLoc);
  if (cbLoc) atomicAdd(&sCB, cbLoc);
  __syncthreads();

  // ---- ZFLAG gate: ctrl region (hist/totals/counters) zeroed past here.
  // Lifecycle-safe (R17-proven); pre-satisfied in practice. ----
  if (tid == 0) {
    while (AG_LOAD(&ws[OFF_ZFLG + grp * 16]) != MAGIC_Z)
      __builtin_amdgcn_s_sleep(2);
  }
  __syncthreads();

  // ---- candidate pushes (post-gate; fanned 64-way lists) ----
  #pragma unroll
  for (int r = 0; r < 2; r++) {
    uint32_t lab = lm[r] >> 24;
    uint32_t m = lm[r] & 0x7FFFFFu;
    bool cand = (lab == LAB_FG) || (lab == LAB_BG && m < BG_TC);
    if (!cand) continue;
    int hw = (hb + r) * 256 + w;
    uint32_t n = (uint32_t)(hw * 9 + a);
    int cls = (lab == LAB_FG) ? 0 : 1;
    uint32_t idx = atomicAdd(
        &ws[(cls ? OFF_CCNTB : OFF_CCNTF) + grp * 16], 1u);
    if (idx < CLCAP) {
      uint64_t* lst = (uint64_t*)(ws + (cls ? OFF_LISTB : OFF_LISTF)) +
                      (uint32_t)grp * CLCAP;
      AG_STORE(&lst[idx], ((uint64_t)m << 20) | (uint64_t)n);
    } else {
      // overflow (P ~ 0): fall back to default; completer never sees it
      out_lab[a * HW + hw] = 2.0f;
      int c4 = a * 4;
      out_wts[(c4 + 0) * HW + hw] = 0.0f;
      out_wts[(c4 + 1) * HW + hw] = 0.0f;
      out_wts[(c4 + 2) * HW + hw] = 0.0f;
      out_wts[(c4 + 3) * HW + hw] = 0.0f;
    }
  }

  // ---- global hist add (~9 atomics/block) + per-block totals ----
  for (int i = tid; i < 2 * NBINS; i += 256) {
    uint32_t v = sh[i];
    if (v) atomicAdd(&ws[OFF_HF + i], v);
  }
  if (tid == 0) {
    if (sCF) atomicAdd(&ws[OFF_TOTF + grp * 16], sCF);
    if (sCB) atomicAdd(&ws[OFF_TOTB + grp * 16], sCB);
  }
  asm volatile("s_waitcnt vmcnt(0)" ::: "memory");
  __syncthreads();

  // ---- barrier B: tree arrival; NON-completers EXIT here ----
  if (tid == 0) {
    int last = 0;
    uint32_t v = atomicAdd(&ws[OFF_SUBB + grp * 16], 1u);
    if (v == GQ - 1) {
      uint32_t r = atomicAdd(&ws[OFF_ROOTB], 1u);
      if (r == NGRP - 1) last = 1;
    }
    sLastB = last;
  }
  __syncthreads();
  if (!sLastB) return;

  // ================= completer (single block) =================
  // totals: 128 counters loaded in parallel, reduced via LDS
  if (tid < NGRP)            sTots[tid] = AG_LOAD(&ws[OFF_TOTF + tid * 16]);
  else if (tid < 2 * NGRP)
    sTots[tid] = AG_LOAD(&ws[OFF_TOTB + (tid - NGRP) * 16]);
  __syncthreads();
  if (tid == 0) {
    uint32_t totF = 0, totB = 0;
    for (int i = 0; i < NGRP; i++) {
      totF += sTots[i]; totB += sTots[NGRP + i];
    }
    uint32_t Kf = totF < CAPK ? totF : CAPK;
    uint32_t Kb = totB < CAPK ? totB : CAPK;
    sTots[0] = totF; sTots[1] = totB;
    sInv = 1.0f / (float)(Kf + Kb);        // 1/num_ni
  }
  __syncthreads();
  uint32_t totF = sTots[0], totB = sTots[1];

  // select per class: parallel hist load + LDS scan -> sSelLoc
  for (int cls = 0; cls < 2; cls++) {
    uint32_t* hist = ws + (cls ? OFF_HB : OFF_HF);
    uint32_t tot = cls ? totB : totF;
    uint32_t K = tot < CAPK ? tot : CAPK;
    uint32_t loc = AG_LOAD(&hist[tid]);      // 1 bin/thread, parallel
    __syncthreads();                         // scB reuse boundary
    sh[tid] = loc; __syncthreads();
    for (int off = 1; off < 256; off <<= 1) {
      uint32_t v = (tid >= off) ? sh[tid - off] : 0u;
      __syncthreads();
      sh[tid] += v;
      __syncthreads();
    }
    if (tid == 0) {
      uint32_t mode = (K == 0u) ? 0u : ((tot <= CAPK) ? 1u : 2u);
      sSelLoc[cls * 5 + 0] = mode;
      sSelLoc[cls * 5 + 1] = 0xFFFFFFFFu;
      sSelLoc[cls * 5 + 2] = 0u;
      sSelLoc[cls * 5 + 3] = 0u;
      sSelLoc[cls * 5 + 4] = K;
    }
    __syncthreads();
    if (K > 0u && tot > CAPK) {
      uint32_t myC = sh[tid], pvC = (tid == 0) ? 0u : sh[tid - 1];
      if (myC >= K && pvC < K) {             // boundary bin = tid
        sSelLoc[cls * 5 + 1] = (uint32_t)tid;
        sSelLoc[cls * 5 + 2] = pvC;
        sSelLoc[cls * 5 + 3] = K - pvC;
      }
    }
    __syncthreads();
  }
  float inv = sInv;

  // candidate processing per class: parallel gather; below-boundary ->
  // kept, boundary-bin -> stage+rank (exact, keys unique), else default.
  for (int cls = 0; cls < 2; cls++) {
    if (tid < NGRP) {
      uint32_t c2 = AG_LOAD(&ws[(cls ? OFF_CCNTB : OFF_CCNTF) + tid * 16]);
      sCnt2[tid] = c2 < CLCAP ? c2 : CLCAP;
    }
    if (tid == 0) sStageCnt = 0u;
    __syncthreads();
    uint32_t mode = sSelLoc[cls * 5 + 0];
    uint32_t bb = sSelLoc[cls * 5 + 1];
    uint32_t need = sSelLoc[cls * 5 + 3];
    const uint64_t* lst0 =
        (const uint64_t*)(ws + (cls ? OFF_LISTB : OFF_LISTF));
    for (uint32_t idx = tid; idx < NGRP * CLCAP; idx += 256) {
      uint32_t g2 = idx >> 7, i = idx & (CLCAP - 1u);    // CLCAP = 128
      if (i >= sCnt2[g2]) continue;
      uint64_t k = AG_LOAD(&lst0[g2 * CLCAP + i]);
      uint32_t m = (uint32_t)(k >> 20);
      uint32_t n = (uint32_t)(k & 0xFFFFFu);
      bool decided = true, kept = false;
      if (mode == 1u) kept = true;
      else if (mode == 2u) {
        uint32_t bn = cls ? (m >> 8) : (m >> 15);
        if (bn < bb) kept = true;
        else if (bn == bb) {
          uint32_t s = atomicAdd(&sStageCnt, 1u);
          if (s < STAGE_CAP) { scB[s] = k; decided = false; }
        }
      }
      if (decided) {
        uint32_t aa = n % 9u, hww = n / 9u;
        uint32_t tt = aa * HW + hww;
        float lv = kept ? (cls == 0 ? 1.0f : 0.0f) : 2.0f;
        float wvv = (kept && cls == 0) ? inv : 0.0f;
        AG_STORE(&out_lab[tt], lv);
        #pragma unroll
        for (int j2 = 0; j2 < 4; j2++)
          AG_STORE(&out_wts[(aa * 4 + j2) * HW + hww], wvv);
      }
    }
    __syncthreads();
    uint32_t C = sStageCnt < STAGE_CAP ? sStageCnt : STAGE_CAP;
    for (uint32_t i = tid; i < C; i += 256) {
      uint64_t k = scB[i];
      uint32_t rr = 0;
      for (uint32_t j = 0; j < C; j++) rr += (scB[j] < k) ? 1u : 0u;
      bool kept = (rr < need);               // keys unique -> exactly need
      uint32_t n = (uint32_t)(k & 0xFFFFFu);
      uint32_t aa = n % 9u, hww = n / 9u;
      uint32_t tt = aa * HW + hww;
      float lv = kept ? (cls == 0 ? 1.0f : 0.0f) : 2.0f;
      float wvv = (kept && cls == 0) ? inv : 0.0f;
      AG_STORE(&out_lab[tt], lv);
      #pragma unroll
      for (int j2 = 0; j2 < 4; j2++)
        AG_STORE(&out_wts[(aa * 4 + j2) * HW + hww], wvv);
    }
    __syncthreads();
  }

  // lifecycle: clear ZFLAG for the next run
  if (tid < NGRP) AG_STORE(&ws[OFF_ZFLG + tid * 16], 0u);
}

extern "C" void kernel_launch(void* const* d_in, const int* in_sizes, int n_in,
                              void* d_out, int out_size, void* d_ws,
                              size_t ws_size, hipStream_t stream) {
  const float* gt  = (const float*)d_in[1];
  const int*   imw = (const int*)d_in[2];
  const int*   imh = (const int*)d_in[3];
  float* out      = (float*)d_out;
  float* out_lab  = out;                   // 589824
  float* out_adj  = out + N_ANCH;          // 4*589824
  float* out_wts  = out + 5 * N_ANCH;      // 4*589824
  uint32_t* ws = (uint32_t*)d_ws;          // ~158 KB used

  uint32_t kf0, kf1, kb0, kb1;
  tf2x32(0u, 42u, 0u, 0u, &kf0, &kf1);
  tf2x32(0u, 42u, 0u, 1u, &kb0, &kb1);

  // SINGLE dispatch. Co-residency (deadlock gate): 1152 blocks, 4 waves
  // each; wave cap 8 blocks/CU x 256 CU = 2048 >= 1152; LDS ~19KB -> 8/CU.
  hipLaunchKernelGGL(k_one, dim3(NBLK), dim3(256), 0, stream, gt, imw, imh,
                     out_lab, out_adj, out_wts, ws, kf0, kf1, kb0, kb1);
}

// Round 17
// 91.263 us; speedup vs baseline: 1.4657x; 1.4657x over previous
//
#include <hip/hip_runtime.h>
#include <stdint.h>

// ===========================================================================
// AnchorDataGenerator (Faster R-CNN anchor target layer), MI355X / gfx950
// Round 20 = Round-17 champion (91.1us, absmax 0) + R19's validated piece
// (compute-time default emit), WITHOUT R19's lone-completer mistake (83us
// single-block tail of dependent AG loads -> rule: never give one block
// O(thousands) of latency-bound agent ops).
// Change vs champion: post-wake emit is CANDIDATES-ONLY.
//   - compute pass writes adj + defaults (2.0/0) for all non-candidates
//     (IGN; BG with m>=BG_TC -- outside top-128 at the same 50-sigma margin
//     the champion's coarse hist already relies on). ~99.4% of anchors done
//     before the wake; stores overlap compute.
//   - post-wake each block resolves only its OWN ~6 candidates (FG; BG with
//     m<BG_TC): below-boundary -> kept; boundary-bin -> push to fixup
//     (champion-proven); above -> default. Distributed, near-free.
//   - barrier D + completer fixup verbatim (~200 keys, exact rank).
// Sync skeleton byte-identical to champion: 576 blocks, ZFLAG poison-safe
// in-kernel init, coarse 256-bin hist, per-block totals, tree barrier B,
// completer select (parallel hist load + LDS scan), fanned CFLG wake,
// tree barrier D, fixup; vmcnt(0) before every arrival RMW.
// ===========================================================================

#define NUM_A 9
#define HW 65536
#define N_ANCH 589824
#define NG 64
#define CAPK 128u
#define NBINS 256
#define BG_TC 65536u                     // BG coarse filter threshold on m
#define CAND_CAP 2048

#define LAB_BG 0u
#define LAB_FG 1u
#define LAB_IGN 2u

#define NBLK 576

// workspace layout (u32 words)
#define OFF_HF    0                      // 256 fg hist (full range, >>15)
#define OFF_HB    256                    // 256 bg hist ([0,2^16), >>8)
#define OFF_TOTF  512                    // 32 x stride16 per-group fg totals
#define OFF_TOTB  1024                   // 32 x stride16 bg totals
#define OFF_SUBB  1536                   // 32 x stride16 barrier-B subs
#define OFF_ROOTB 2048                   // (pad 16)
#define OFF_SUBD  2064                   // 32 x stride16 barrier-D subs
#define OFF_ROOTD 2576                   // (pad 16)
#define OFF_SEL   2592                   // 10 used: {mode,bin,below,need,K}x2
#define OFF_CFLG  2608                   // 32 x stride16 wake flags
#define OFF_CNTF  3120                   // candidate counter fg (pad 16)
#define OFF_CNTB  3136                   // candidate counter bg (pad 16)
#define CTRL_WORDS 3152                  // zeroed by block 0 (AG stores)
#define OFF_ZFLG  CTRL_WORDS             // 3152: 32 x stride16, NOT zeroed
                                         //   by block 0; completer clears
#define OFF_CANDF (OFF_ZFLG + 32*16)     // 3664 (byte 14656, 8B aligned)
#define OFF_CANDB (OFF_CANDF + 2*CAND_CAP)   // 7760; end 11856 (~47 KB)

#define MAGIC_C 0x5CA1AB1Eu
#define MAGIC_Z 0x7A3F19C5u

__constant__ float BA[NUM_A][4] = {
  { -84.f,  -40.f,  99.f,  55.f}, {-176.f,  -88.f, 191.f, 103.f},
  {-360.f, -184.f, 375.f, 199.f}, { -56.f,  -56.f,  71.f,  71.f},
  {-120.f, -120.f, 135.f, 135.f}, {-248.f, -248.f, 263.f, 263.f},
  { -36.f,  -80.f,  51.f,  95.f}, { -80.f, -168.f,  95.f, 183.f},
  {-168.f, -344.f, 183.f, 359.f}};

__host__ __device__ static inline void tf2x32(uint32_t k0, uint32_t k1,
                                              uint32_t x0, uint32_t x1,
                                              uint32_t* o0, uint32_t* o1) {
  const uint32_t ks2 = k0 ^ k1 ^ 0x1BD11BDAu;
#define TF_R(r) { x0 += x1; x1 = (x1 << (r)) | (x1 >> (32 - (r))); x1 ^= x0; }
  x0 += k0; x1 += k1;
  TF_R(13) TF_R(15) TF_R(26) TF_R(6)
  x0 += k1;  x1 += ks2 + 1u;
  TF_R(17) TF_R(29) TF_R(16) TF_R(24)
  x0 += ks2; x1 += k0 + 2u;
  TF_R(13) TF_R(15) TF_R(26) TF_R(6)
  x0 += k0;  x1 += k1 + 3u;
  TF_R(17) TF_R(29) TF_R(16) TF_R(24)
  x0 += k1;  x1 += ks2 + 4u;
  TF_R(13) TF_R(15) TF_R(26) TF_R(6)
  x0 += ks2; x1 += k0 + 5u;
#undef TF_R
  *o0 = x0; *o1 = x1;
}

__device__ static inline uint32_t mant_of(uint32_t k0, uint32_t k1, uint32_t n) {
  uint32_t o0, o1;
  tf2x32(k0, k1, 0u, n, &o0, &o1);
  return (o0 ^ o1) >> 9;                 // 23-bit mantissa
}

// Max of fl(iw) over valid integer shifts [lo,hi] for one axis (concave,
// unimodal; max at clamped floor/ceil of continuous argmax endpoints).
__device__ static inline float axis_best(float blo, float bhi, float glo,
                                         float ghi, int lo, int hi) {
  #pragma clang fp contract(off)
  float t1 = (ghi - bhi) * 0.0625f;
  float t2 = (glo - blo) * 0.0625f;
  float tmin = fminf(t1, t2), tmax = fmaxf(t1, t2);
  int c1 = (int)floorf(tmin), c2 = (int)ceilf(tmax);
  int cand0 = lo, cand1 = hi;
  int cand2 = min(max(c1,     lo), hi);
  int cand3 = min(max(c1 + 1, lo), hi);
  int cand4 = min(max(c2 - 1, lo), hi);
  int cand5 = min(max(c2,     lo), hi);
  float best = -3.0e38f;
  int cands[6] = {cand0, cand1, cand2, cand3, cand4, cand5};
  #pragma unroll
  for (int i = 0; i < 6; i++) {
    float s = (float)(cands[i] << 4);
    float v = fminf(bhi + s, ghi) - fmaxf(blo + s, glo) + 1.0f;
    best = fmaxf(best, v);
  }
  return best;
}

#define AG_LOAD(p)      __hip_atomic_load((p), __ATOMIC_RELAXED, __HIP_MEMORY_SCOPE_AGENT)
#define AG_STORE(p, v)  __hip_atomic_store((p), (v), __ATOMIC_RELAXED, __HIP_MEMORY_SCOPE_AGENT)

__global__ __launch_bounds__(256) void k_one(const float* __restrict__ gt,
                                             const int* __restrict__ imw_p,
                                             const int* __restrict__ imh_p,
                                             float* __restrict__ out_lab,
                                             float* __restrict__ out_adj,
                                             float* __restrict__ out_wts,
                                             uint32_t* __restrict__ ws,
                                             uint32_t kf0, uint32_t kf1,
                                             uint32_t kb0, uint32_t kb1) {
  #pragma clang fp contract(off)
  __shared__ uint64_t scB[CAND_CAP];         // 16 KB; hist+scan view aliased
  uint32_t* sh = (uint32_t*)scB;             // [0..511] LDS hist, scan buf
  __shared__ float sg0[NG], sg1[NG], sg2[NG], sg3[NG], sga[NG], sgm[NG];
  __shared__ uint32_t sgmU[NG];
  __shared__ unsigned long long sMask[4];
  __shared__ int sAnyZero, sLastB, sLastD;
  __shared__ uint32_t sSel[10];
  __shared__ uint32_t sCF, sCB;
  int tid = threadIdx.x;
  int b = blockIdx.x;
  int a = b >> 6, hb = (b & 63) << 2;        // anchor type, rows hb..hb+3

  // ---- block 0: zero ctrl region (AGENT-scope stores -> performed at IF,
  // no dirty-L2 clobber), then publish fanned ZFLAG = MAGIC_Z ----
  if (b == 0) {
    for (int i = tid; i < CTRL_WORDS; i += 256) AG_STORE(&ws[i], 0u);
    asm volatile("s_waitcnt vmcnt(0)" ::: "memory");
    __syncthreads();                         // all zero-stores at IF
    if (tid < 32) AG_STORE(&ws[OFF_ZFLG + tid * 16], MAGIC_Z);
  }

  ((uint2*)sh)[tid] = make_uint2(0, 0);      // zero 512-word LDS hist
  if (tid == 0) { sAnyZero = 0; sCF = 0u; sCB = 0u; }
  if (tid < NG) {
    const float4 g4 = ((const float4*)gt)[tid];
    sg0[tid] = g4.x; sg1[tid] = g4.y; sg2[tid] = g4.z; sg3[tid] = g4.w;
    float gw = g4.z - g4.x + 1.0f, gh = g4.w - g4.y + 1.0f;
    sga[tid] = (gw > 0.0f && gh > 0.0f) ? gw * gh : 0.0f;
    sgmU[tid] = 0u;
  }
  __syncthreads();   // S1

  // ---- local analytic gmax (LDS atomicMax on float bits; IoU >= 0) ----
  {
    int imwi = imw_p[0], imhi = imh_p[0];
    for (int p = tid; p < NG * NUM_A; p += 256) {
      int g = p / NUM_A, q = p - g * NUM_A;
      float b0 = BA[q][0], b1 = BA[q][1], b2 = BA[q][2], b3 = BA[q][3];
      int ib0 = (int)b0, ib1 = (int)b1, ib2 = (int)b2, ib3 = (int)b3;
      int wlo = max(0, (-ib0 + 15) >> 4);
      int whi = min(255, (imwi - ib2 - 1) >> 4);
      int hlo = max(0, (-ib1 + 15) >> 4);
      int hhi = min(255, (imhi - ib3 - 1) >> 4);
      if (wlo > whi || hlo > hhi) continue;
      float iwb = axis_best(b0, b2, sg0[g], sg2[g], wlo, whi);
      float ihb = axis_best(b1, b3, sg1[g], sg3[g], hlo, hhi);
      float aw = b2 - b0 + 1.0f, ah = b3 - b1 + 1.0f;
      float aarea = aw * ah;
      float inter = (iwb > 0.0f && ihb > 0.0f) ? iwb * ihb : 0.0f;
      float den = aarea + sga[g] - inter;
      float o = inter / den;
      atomicMax(&sgmU[g], __float_as_uint(o));
    }
  }

  // per-wave y-mask
  {
    int wv = tid >> 6, g = tid & 63;
    float sy = (float)((hb + wv) << 4);
    float ihp = fminf(BA[a][3] + sy, sg3[g]) - fmaxf(BA[a][1] + sy, sg1[g]) + 1.0f;
    unsigned long long mk = __ballot(ihp > 0.0f);
    if (g == 0) sMask[wv] = mk;
  }
  __syncthreads();   // S2
  if (tid < NG) {
    uint32_t mm = sgmU[tid];
    sgm[tid] = __uint_as_float(mm);
    if (mm == 0u) atomicOr(&sAnyZero, 1);
  }
  __syncthreads();   // S3

  float BA0 = BA[a][0], BA1 = BA[a][1], BA2 = BA[a][2], BA3 = BA[a][3];
  float imw = (float)imw_p[0], imh = (float)imh_p[0];
  int w = tid;
  float sx = (float)(w << 4);
  float A0 = BA0 + sx, A2 = BA2 + sx;
  float aw = A2 - A0 + 1.0f;
  float A1v[4], A3v[4];
  #pragma unroll
  for (int r = 0; r < 4; r++) {
    float sy = (float)((hb + r) << 4);
    A1v[r] = BA1 + sy; A3v[r] = BA3 + sy;
  }
  float ah = A3v[0] - A1v[0] + 1.0f;
  float aarea = aw * ah;                   // exact ints -> bit-exact
  bool xv = (A0 >= 0.0f) && (A2 < imw);

  unsigned long long mk0 = sMask[0], mk1 = sMask[1],
                     mk2 = sMask[2], mk3 = sMask[3];
  unsigned long long uni = mk0 | mk1 | mk2 | mk3;
  float amaxv[4] = {0.f, 0.f, 0.f, 0.f};
  int bgv[4] = {0, 0, 0, 0};
  uint32_t afv = 0u;
  while (uni) {
    int g = __ffsll(uni) - 1;
    uni &= uni - 1;
    float iw = fminf(A2, sg2[g]) - fmaxf(A0, sg0[g]) + 1.0f;
    if (!__any(iw > 0.0f)) continue;
    if (iw > 0.0f) {
      float base = aarea + sga[g];
      float gy1 = sg1[g], gy2 = sg3[g], gm = sgm[g];
#define DO_ROW(r, mk)                                                     \
      if ((mk >> g) & 1ull) {                                             \
        float ih = fminf(A3v[r], gy2) - fmaxf(A1v[r], gy1) + 1.0f;        \
        float inter = iw * ih;                                            \
        float o = inter / (base - inter);                                 \
        if (o > amaxv[r]) { amaxv[r] = o; bgv[r] = g; }                   \
        if (o == gm) afv |= (1u << r);                                    \
      }
      DO_ROW(0, mk0) DO_ROW(1, mk1) DO_ROW(2, mk2) DO_ROW(3, mk3)
#undef DO_ROW
    }
  }

  bool anyZ = (sAnyZero != 0);
  uint32_t lm[4];
  uint32_t cfLoc = 0, cbLoc = 0;
  #pragma unroll
  for (int r = 0; r < 4; r++) {
    int hw = (hb + r) * 256 + w;
    bool valid = xv && (A1v[r] >= 0.0f) && (A3v[r] < imh);
    float amax = amaxv[r];
    bool anyfg = (((afv >> r) & 1u) || anyZ) && valid;
    uint32_t lab;
    if (!valid)                       lab = LAB_IGN;
    else if (anyfg || amax >= 0.7f)   lab = LAB_FG;
    else if (amax < 0.3f)             lab = LAB_BG;
    else                              lab = LAB_IGN;

    float adj0 = 0.f, adj1 = 0.f, adj2 = 0.f, adj3 = 0.f;
    if (valid) {
      int bg = bgv[r];
      float G0 = sg0[bg], G1 = sg1[bg], G2 = sg2[bg], G3 = sg3[bg];
      float ax = (A2 + A0) * 0.5f, ay = (A3v[r] + A1v[r]) * 0.5f;
      float gwm = G2 - G0 + 1.0f, ghm = G3 - G1 + 1.0f;
      float gx = (G2 + G0) * 0.5f, gy = (G3 + G1) * 0.5f;
      adj0 = (gx - ax) / aw;
      adj1 = (gy - ay) / ah;
      adj2 = logf(gwm / aw);
      adj3 = logf(ghm / ah);
    }
    int c4 = a * 4;
    out_adj[(c4 + 0) * HW + hw] = adj0;
    out_adj[(c4 + 1) * HW + hw] = adj1;
    out_adj[(c4 + 2) * HW + hw] = adj2;
    out_adj[(c4 + 3) * HW + hw] = adj3;

    uint32_t m = 0u;
    uint32_t n = (uint32_t)(hw * 9 + a);   // original anchor index (tie-break)
    if (lab != LAB_IGN) {
      uint32_t kk0 = (lab == LAB_FG) ? kf0 : kb0;
      uint32_t kk1 = (lab == LAB_FG) ? kf1 : kb1;
      m = mant_of(kk0, kk1, n);
      if (lab == LAB_FG) {
        cfLoc++;
        atomicAdd(&sh[m >> 15], 1u);                   // FG: full range >>15
      } else {
        cbLoc++;
        if (m < BG_TC) atomicAdd(&sh[NBINS + (m >> 8)], 1u);  // BG: coarse
      }
    }
    lm[r] = (lab << 24) | m;                 // stays in registers

    // default emit for non-candidates: select-independent, overlaps compute.
    // Candidates (FG; BG with m<BG_TC) resolved post-wake (disjoint writers).
    bool cand = (lab == LAB_FG) || (lab == LAB_BG && m < BG_TC);
    if (!cand) {
      out_lab[a * HW + hw] = 2.0f;
      out_wts[(c4 + 0) * HW + hw] = 0.0f;
      out_wts[(c4 + 1) * HW + hw] = 0.0f;
      out_wts[(c4 + 2) * HW + hw] = 0.0f;
      out_wts[(c4 + 3) * HW + hw] = 0.0f;
    }
  }
  if (cfLoc) atomicAdd(&sCF, cfLoc);
  if (cbLoc) atomicAdd(&sCB, cbLoc);
  __syncthreads();

  // ---- ZFLAG gate: ctrl region guaranteed zeroed past this point.
  // Lifecycle-safe (R17-proven). Pre-satisfied in practice. ----
  if (tid == 0) {
    while (AG_LOAD(&ws[OFF_ZFLG + (b & 31) * 16]) != MAGIC_Z)
      __builtin_amdgcn_s_sleep(2);
  }
  __syncthreads();

  // ---- global hist add (~9 atomics/block) + per-block totals ----
  for (int i = tid; i < 2 * NBINS; i += 256) {
    uint32_t v = sh[i];
    if (v) atomicAdd(&ws[OFF_HF + i], v);
  }
  if (tid == 0) {
    if (sCF) atomicAdd(&ws[OFF_TOTF + (b & 31) * 16], sCF);
    if (sCB) atomicAdd(&ws[OFF_TOTB + (b & 31) * 16], sCB);
  }
  asm volatile("s_waitcnt vmcnt(0)" ::: "memory");
  __syncthreads();

  // ---- barrier B: tree arrival; completer runs select ----
  if (tid == 0) {
    int last = 0;
    uint32_t v = atomicAdd(&ws[OFF_SUBB + (b & 31) * 16], 1u);
    if (v == 17u) {
      uint32_t r = atomicAdd(&ws[OFF_ROOTB], 1u);
      if (r == 31u) last = 1;
    }
    sLastB = last;
  }
  __syncthreads();
  if (sLastB) {
    // totals: 64 counters loaded in parallel, reduced via LDS
    __shared__ uint32_t sTots[64];
    if (tid < 32)       sTots[tid] = AG_LOAD(&ws[OFF_TOTF + tid * 16]);
    else if (tid < 64)  sTots[tid] = AG_LOAD(&ws[OFF_TOTB + (tid - 32) * 16]);
    __syncthreads();
    uint32_t totF = 0, totB = 0;
    if (tid == 0) {
      for (int i = 0; i < 32; i++) { totF += sTots[i]; totB += sTots[32 + i]; }
      sTots[0] = totF; sTots[1] = totB;
    }
    __syncthreads();
    totF = sTots[0]; totB = sTots[1];

    for (int cls = 0; cls < 2; cls++) {
      uint32_t* hist = ws + (cls ? OFF_HB : OFF_HF);
      uint32_t* sel = ws + OFF_SEL + cls * 5;
      uint32_t tot = cls ? totB : totF;
      uint32_t K = tot < CAPK ? tot : CAPK;
      uint32_t loc = AG_LOAD(&hist[tid]);      // 1 bin/thread, parallel
      sh[tid] = loc; __syncthreads();
      for (int off = 1; off < 256; off <<= 1) {
        uint32_t v = (tid >= off) ? sh[tid - off] : 0u;
        __syncthreads();
        sh[tid] += v;
        __syncthreads();
      }
      if (tid == 0) {
        uint32_t mode = (K == 0u) ? 0u : ((tot <= CAPK) ? 1u : 2u);
        AG_STORE(&sel[0], mode);
        AG_STORE(&sel[4], K);
        if (mode != 2u) {
          AG_STORE(&sel[1], 0xFFFFFFFFu); AG_STORE(&sel[2], 0u);
          AG_STORE(&sel[3], 0u);
        }
      }
      if (K > 0u && tot > CAPK) {
        uint32_t myC = sh[tid], pvC = (tid == 0) ? 0u : sh[tid - 1];
        if (myC >= K && pvC < K) {            // boundary bin = tid
          AG_STORE(&sel[1], (uint32_t)tid); AG_STORE(&sel[2], pvC);
          AG_STORE(&sel[3], K - pvC);
        }
      }
      __syncthreads();
    }
    asm volatile("s_waitcnt vmcnt(0)" ::: "memory");
    __syncthreads();                         // all SEL stores at IF
    if (tid < 32) AG_STORE(&ws[OFF_CFLG + tid * 16], MAGIC_C);
  }

  // ---- fanned-out wake: poll OWN sub-flag (<=18 pollers/address) ----
  if (tid == 0) {
    while (AG_LOAD(&ws[OFF_CFLG + (b & 31) * 16]) != MAGIC_C)
      __builtin_amdgcn_s_sleep(2);
  }
  __syncthreads();
  if (tid < 10) sSel[tid] = AG_LOAD(&ws[OFF_SEL + tid]);
  __syncthreads();
  uint32_t mF = sSel[0], bbF = sSel[1];
  uint32_t mB = sSel[5], bbB = sSel[6];
  uint32_t Kf = sSel[4], Kb = sSel[9];
  float inv = 1.0f / (float)(Kf + Kb);       // 1/num_ni

  // ---- post-wake: CANDIDATES ONLY (~6/block); boundary-bin -> fixup ----
  #pragma unroll
  for (int r = 0; r < 4; r++) {
    uint32_t lab = lm[r] >> 24;
    uint32_t m = lm[r] & 0x7FFFFFu;
    bool cand = (lab == LAB_FG) || (lab == LAB_BG && m < BG_TC);
    if (!cand) continue;
    int hw = (hb + r) * 256 + w;
    uint32_t n = (uint32_t)(hw * 9 + a);
    float outv = 2.0f, wv = 0.0f;
    bool skip = false;                        // true -> fixup sole writer
    if (lab == LAB_FG) {
      if (mF == 1u) { outv = 1.0f; wv = inv; }
      else if (mF == 2u) {
        uint32_t bn = m >> 15;
        if (bn < bbF) { outv = 1.0f; wv = inv; }
        else if (bn == bbF) {
          uint32_t idx = atomicAdd(&ws[OFF_CNTF], 1u);
          if (idx < CAND_CAP) {
            AG_STORE((uint64_t*)(ws + OFF_CANDF) + idx,
                     ((uint64_t)m << 20) | (uint64_t)n);
            skip = true;
          }
        }
      }
    } else {                                  // LAB_BG, m < BG_TC
      if (mB == 1u) { outv = 0.0f; }
      else if (mB == 2u) {
        uint32_t bn = m >> 8;
        if (bn < bbB) { outv = 0.0f; }
        else if (bn == bbB) {
          uint32_t idx = atomicAdd(&ws[OFF_CNTB], 1u);
          if (idx < CAND_CAP) {
            AG_STORE((uint64_t*)(ws + OFF_CANDB) + idx,
                     ((uint64_t)m << 20) | (uint64_t)n);
            skip = true;
          }
        }
      }
    }
    if (!skip) {
      out_lab[a * HW + hw] = outv;
      int c4 = a * 4;
      out_wts[(c4 + 0) * HW + hw] = wv;
      out_wts[(c4 + 1) * HW + hw] = wv;
      out_wts[(c4 + 2) * HW + hw] = wv;
      out_wts[(c4 + 3) * HW + hw] = wv;
    }
  }

  asm volatile("s_waitcnt vmcnt(0)" ::: "memory");
  __syncthreads();

  // ---- barrier D: tree arrival; completer runs fixup; others exit ----
  if (tid == 0) {
    int last = 0;
    uint32_t v = atomicAdd(&ws[OFF_SUBD + (b & 31) * 16], 1u);
    if (v == 17u) {
      uint32_t r = atomicAdd(&ws[OFF_ROOTD], 1u);
      if (r == 31u) last = 1;
    }
    sLastD = last;
  }
  __syncthreads();
  if (sLastD) {
    for (int cls = 0; cls < 2; cls++) {
      uint32_t cnt = AG_LOAD(&ws[cls == 0 ? OFF_CNTF : OFF_CNTB]);
      uint32_t C = cnt < CAND_CAP ? cnt : CAND_CAP;
      uint32_t need = AG_LOAD(&ws[OFF_SEL + cls * 5 + 3]);
      const uint64_t* cand =
          (const uint64_t*)(ws + (cls == 0 ? OFF_CANDF : OFF_CANDB));
      for (uint32_t i = tid; i < C; i += 256)
        scB[i] = AG_LOAD(&cand[i]);           // parallel gather (R13 lesson)
      __syncthreads();
      for (uint32_t i = tid; i < C; i += 256) {
        uint64_t k = scB[i];
        uint32_t rr = 0;
        for (uint32_t j = 0; j < C; j++) rr += (scB[j] < k) ? 1u : 0u;
        bool kept = (rr < need);             // keys unique -> exactly need
        uint32_t nn = (uint32_t)(k & 0xFFFFFu);
        uint32_t aa = nn % 9u, hww = nn / 9u;
        uint32_t tt = aa * HW + hww;
        float lv = kept ? (cls == 0 ? 1.0f : 0.0f) : 2.0f;
        float wvv = (kept && cls == 0) ? inv : 0.0f;
        AG_STORE(&out_lab[tt], lv);
        #pragma unroll
        for (int j2 = 0; j2 < 4; j2++)
          AG_STORE(&out_wts[(aa * 4 + j2) * HW + hww], wvv);
      }
      __syncthreads();
    }
    // ---- lifecycle: clear ZFLAG for the next run ----
    if (tid < 32) AG_STORE(&ws[OFF_ZFLG + tid * 16], 0u);
  }
}

extern "C" void kernel_launch(void* const* d_in, const int* in_sizes, int n_in,
                              void* d_out, int out_size, void* d_ws,
                              size_t ws_size, hipStream_t stream) {
  const float* gt  = (const float*)d_in[1];
  const int*   imw = (const int*)d_in[2];
  const int*   imh = (const int*)d_in[3];
  float* out      = (float*)d_out;
  float* out_lab  = out;                   // 589824
  float* out_adj  = out + N_ANCH;          // 4*589824
  float* out_wts  = out + 5 * N_ANCH;      // 4*589824
  uint32_t* ws = (uint32_t*)d_ws;          // ~47 KB used

  uint32_t kf0, kf1, kb0, kb1;
  tf2x32(0u, 42u, 0u, 0u, &kf0, &kf1);
  tf2x32(0u, 42u, 0u, 1u, &kb0, &kb1);

  // SINGLE dispatch (champion structure). Residency: 576 blocks, ~19KB LDS
  // -> 8 blocks/CU (2048 slots) >> 576; sole kernel -> all co-resident.
  hipLaunchKernelGGL(k_one, dim3(NBLK), dim3(256), 0, stream, gt, imw, imh,
                     out_lab, out_adj, out_wts, ws, kf0, kf1, kb0, kb1);
}